// Round 2
// baseline (3681.481 us; speedup 1.0000x reference)
//
#include <hip/hip_runtime.h>
#include <math.h>

// B=4096 rows, V=32000 cols (fp32). Two-phase plan:
//   A: per-row streaming (BW-bound) -> max, sum(t*x), compacted active set to d_ws
//   B: one wave per row, register-resident bisection (50 iters) -> loss atomicAdd
constexpr int V_DIM  = 32000;
constexpr int NV4    = V_DIM / 4;              // 8000 float4/row
constexpr int TPB_A  = 1024;                   // 16 waves
constexpr int NCHUNK = (NV4 + TPB_A - 1) / TPB_A;  // 8
constexpr int CAP    = 2048;                   // active-set cap (n_act ~450 typ, <1800 worst)
constexpr int N_ITER = 50;

__global__ void zero_out_kernel(float* out) { out[0] = 0.0f; }

// ---------------------------------------------------------------- Kernel A
__global__ __launch_bounds__(TPB_A) void rowstat_kernel(
    const float* __restrict__ X, const float* __restrict__ T,
    float* __restrict__ out, int* __restrict__ cnt_g,
    float* __restrict__ maxs_g, float* __restrict__ act_g, float invB)
{
  const int row = blockIdx.x;
  const float4* X4 = (const float4*)(X + (size_t)row * V_DIM);
  const float4* T4 = (const float4*)(T + (size_t)row * V_DIM);
  const int tid = threadIdx.x, lane = tid & 63, wid = tid >> 6;

  __shared__ float s_wmax[16], s_wsum[16], s_res[2];
  __shared__ int   s_cnt;
  __shared__ float s_act[CAP];

  // pass 1: stream X,T -> row max(x), sum(t*x)
  float tmax = -INFINITY, ttx = 0.0f;
#pragma unroll
  for (int j = 0; j < NCHUNK; ++j) {
    const int idx = tid + j * TPB_A;
    if (idx < NV4) {
      const float4 x = X4[idx];
      const float4 t = T4[idx];
      tmax = fmaxf(tmax, fmaxf(fmaxf(x.x, x.y), fmaxf(x.z, x.w)));
      ttx = fmaf(x.x, t.x, fmaf(x.y, t.y, fmaf(x.z, t.z, fmaf(x.w, t.w, ttx))));
    }
  }
#pragma unroll
  for (int o = 32; o >= 1; o >>= 1) {
    tmax = fmaxf(tmax, __shfl_xor(tmax, o));
    ttx += __shfl_xor(ttx, o);
  }
  if (lane == 0) { s_wmax[wid] = tmax; s_wsum[wid] = ttx; }
  if (tid == 0)  { s_cnt = 0; }
  __syncthreads();
  if (wid == 0) {
    float m = (lane < 16) ? s_wmax[lane] : -INFINITY;
    float s = (lane < 16) ? s_wsum[lane] : 0.0f;
#pragma unroll
    for (int o = 8; o >= 1; o >>= 1) {
      m = fmaxf(m, __shfl_xor(m, o));
      s += __shfl_xor(s, o);
    }
    if (lane == 0) { s_res[0] = m; s_res[1] = s; }
  }
  __syncthreads();

  const float maxX = s_res[0];
  const float thr  = maxX - 2.0f;   // active iff x > max-2  (xs > maxXs-1 = tau_lo_init)

  // pass 2: compact actives (re-read X; row is L2-resident). store xs = 0.5*x
#pragma unroll
  for (int j = 0; j < NCHUNK; ++j) {
    const int idx = tid + j * TPB_A;
    if (idx < NV4) {
      const float4 x = X4[idx];
      if (x.x > thr) { int i = atomicAdd(&s_cnt, 1); if (i < CAP) s_act[i] = 0.5f * x.x; }
      if (x.y > thr) { int i = atomicAdd(&s_cnt, 1); if (i < CAP) s_act[i] = 0.5f * x.y; }
      if (x.z > thr) { int i = atomicAdd(&s_cnt, 1); if (i < CAP) s_act[i] = 0.5f * x.z; }
      if (x.w > thr) { int i = atomicAdd(&s_cnt, 1); if (i < CAP) s_act[i] = 0.5f * x.w; }
    }
  }
  __syncthreads();

  const int cnt = s_cnt;
  const int m   = min(cnt, CAP);
  for (int i = tid; i < m; i += TPB_A) act_g[(size_t)row * CAP + i] = s_act[i];
  if (tid == 0) {
    cnt_g[row]  = cnt;
    maxs_g[row] = 0.5f * maxX;
    atomicAdd(out, -s_res[1] * invB);   // -sum(t*x)/B folded here
  }
}

// ---------------------------------------------------------------- Kernel B
template <int R>
__device__ __forceinline__ float wave_row_loss(const float (&va)[R], float maxXs)
{
  const float tau_hi = maxXs - sqrtf(1.0f / (float)V_DIM);  // (1/d)^(alpha-1)
  float tau_lo = maxXs - 1.0f;

  float s = 0.0f;
#pragma unroll
  for (int j = 0; j < R; ++j) { float r = fmaxf(va[j] - tau_lo, 0.0f); s = fmaf(r, r, s); }
#pragma unroll
  for (int o = 32; o >= 1; o >>= 1) s += __shfl_xor(s, o);
  const float f_lo = s - 1.0f;

  float dm = tau_hi - tau_lo, tau_m = tau_lo;
  for (int it = 0; it < N_ITER; ++it) {
    dm *= 0.5f;
    tau_m = tau_lo + dm;
    float sm = 0.0f;
#pragma unroll
    for (int j = 0; j < R; ++j) { float r = fmaxf(va[j] - tau_m, 0.0f); sm = fmaf(r, r, sm); }
#pragma unroll
    for (int o = 32; o >= 1; o >>= 1) sm += __shfl_xor(sm, o);
    if ((sm - 1.0f) * f_lo >= 0.0f) tau_lo = tau_m;  // uniform across wave
  }

  float S = 0.0f, Q3 = 0.0f, PX = 0.0f;
#pragma unroll
  for (int j = 0; j < R; ++j) {
    const float r = fmaxf(va[j] - tau_m, 0.0f);
    const float r2 = r * r;
    S += r2; Q3 += r2 * r; PX = fmaf(r2, 2.0f * va[j], PX);
  }
#pragma unroll
  for (int o = 32; o >= 1; o >>= 1) {
    S += __shfl_xor(S, o); Q3 += __shfl_xor(Q3, o); PX += __shfl_xor(PX, o);
  }
  return (1.0f - Q3 / (S * sqrtf(S))) * (1.0f / 0.75f) + PX / S;
}

__device__ float wave_row_loss_global(const float* __restrict__ Xr, float maxXs)
{
  const int lane = threadIdx.x & 63;
  const float tau_hi = maxXs - sqrtf(1.0f / (float)V_DIM);
  float tau_lo = maxXs - 1.0f;

  float s = 0.0f;
  for (int i = lane; i < V_DIM; i += 64) {
    float r = fmaxf(0.5f * Xr[i] - tau_lo, 0.0f); s = fmaf(r, r, s);
  }
#pragma unroll
  for (int o = 32; o >= 1; o >>= 1) s += __shfl_xor(s, o);
  const float f_lo = s - 1.0f;

  float dm = tau_hi - tau_lo, tau_m = tau_lo;
  for (int it = 0; it < N_ITER; ++it) {
    dm *= 0.5f; tau_m = tau_lo + dm;
    float sm = 0.0f;
    for (int i = lane; i < V_DIM; i += 64) {
      float r = fmaxf(0.5f * Xr[i] - tau_m, 0.0f); sm = fmaf(r, r, sm);
    }
#pragma unroll
    for (int o = 32; o >= 1; o >>= 1) sm += __shfl_xor(sm, o);
    if ((sm - 1.0f) * f_lo >= 0.0f) tau_lo = tau_m;
  }
  float S = 0.0f, Q3 = 0.0f, PX = 0.0f;
  for (int i = lane; i < V_DIM; i += 64) {
    const float xs = 0.5f * Xr[i];
    const float r = fmaxf(xs - tau_m, 0.0f);
    const float r2 = r * r;
    S += r2; Q3 += r2 * r; PX = fmaf(r2, 2.0f * xs, PX);
  }
#pragma unroll
  for (int o = 32; o >= 1; o >>= 1) {
    S += __shfl_xor(S, o); Q3 += __shfl_xor(Q3, o); PX += __shfl_xor(PX, o);
  }
  return (1.0f - Q3 / (S * sqrtf(S))) * (1.0f / 0.75f) + PX / S;
}

__global__ __launch_bounds__(256) void bisect_kernel(
    const float* __restrict__ X, const int* __restrict__ cnt_g,
    const float* __restrict__ maxs_g, const float* __restrict__ act_g,
    float* __restrict__ out, int nrows, float invB)
{
  const int wid = threadIdx.x >> 6, lane = threadIdx.x & 63;
  const int row = blockIdx.x * 4 + wid;
  if (row >= nrows) return;
  const int   n     = cnt_g[row];
  const float maxXs = maxs_g[row];
  const float* act  = act_g + (size_t)row * CAP;

  float loss;
  if (n <= 512) {                       // typical: n ~ 450
    float va[8];
#pragma unroll
    for (int j = 0; j < 8; ++j) { int idx = j * 64 + lane; va[j] = (idx < n) ? act[idx] : -1e30f; }
    loss = wave_row_loss<8>(va, maxXs);
  } else if (n <= CAP) {
    float va[32];
#pragma unroll
    for (int j = 0; j < 32; ++j) { int idx = j * 64 + lane; va[j] = (idx < n) ? act[idx] : -1e30f; }
    loss = wave_row_loss<32>(va, maxXs);
  } else {                              // statistically never: full-row rescan
    loss = wave_row_loss_global(X + (size_t)row * V_DIM, maxXs);
  }
  if (lane == 0) atomicAdd(out, loss * invB);
}

// ---------------------------------------------------- monolithic fallback (round-1)
__global__ __launch_bounds__(TPB_A) void entmax_loss_kernel(
    const float* __restrict__ X, const float* __restrict__ T,
    float* __restrict__ out, int B)
{
  const int row = blockIdx.x;
  const float*  Xr = X + (size_t)row * V_DIM;
  const float4* X4 = (const float4*)Xr;
  const float4* T4 = (const float4*)(T + (size_t)row * V_DIM);
  const int tid = threadIdx.x, lane = tid & 63, wid = tid >> 6;

  __shared__ float s_wmax[16], s_wsum[16], s_res[2];
  __shared__ int   s_cnt;
  __shared__ float s_act[CAP];

  float tmax = -INFINITY, ttx = 0.0f;
#pragma unroll
  for (int j = 0; j < NCHUNK; ++j) {
    const int idx = tid + j * TPB_A;
    if (idx < NV4) {
      const float4 x = X4[idx], t = T4[idx];
      tmax = fmaxf(tmax, fmaxf(fmaxf(x.x, x.y), fmaxf(x.z, x.w)));
      ttx += x.x * t.x + x.y * t.y + x.z * t.z + x.w * t.w;
    }
  }
#pragma unroll
  for (int o = 32; o >= 1; o >>= 1) {
    tmax = fmaxf(tmax, __shfl_xor(tmax, o));
    ttx += __shfl_xor(ttx, o);
  }
  if (lane == 0) { s_wmax[wid] = tmax; s_wsum[wid] = ttx; }
  if (tid == 0)  { s_cnt = 0; }
  __syncthreads();
  if (wid == 0) {
    float m = (lane < 16) ? s_wmax[lane] : -INFINITY;
    float s = (lane < 16) ? s_wsum[lane] : 0.0f;
#pragma unroll
    for (int o = 8; o >= 1; o >>= 1) { m = fmaxf(m, __shfl_xor(m, o)); s += __shfl_xor(s, o); }
    if (lane == 0) { s_res[0] = m; s_res[1] = s; }
  }
  __syncthreads();

  const float maxX = s_res[0], sum_tx = s_res[1], thr = maxX - 2.0f;
#pragma unroll
  for (int j = 0; j < NCHUNK; ++j) {
    const int idx = tid + j * TPB_A;
    if (idx < NV4) {
      const float4 x = X4[idx];
      if (x.x > thr) { int i = atomicAdd(&s_cnt, 1); if (i < CAP) s_act[i] = 0.5f * x.x; }
      if (x.y > thr) { int i = atomicAdd(&s_cnt, 1); if (i < CAP) s_act[i] = 0.5f * x.y; }
      if (x.z > thr) { int i = atomicAdd(&s_cnt, 1); if (i < CAP) s_act[i] = 0.5f * x.z; }
      if (x.w > thr) { int i = atomicAdd(&s_cnt, 1); if (i < CAP) s_act[i] = 0.5f * x.w; }
    }
  }
  __syncthreads();

  if (wid == 0) {
    const int  n_act = s_cnt;
    const bool use_lds = (n_act <= CAP);
    const int  n = use_lds ? n_act : V_DIM;
    const float maxXs = 0.5f * maxX;
    const float tau_hi = maxXs - sqrtf(1.0f / (float)V_DIM);
    float tau_lo = maxXs - 1.0f;

    float s = 0.0f;
    for (int i = lane; i < n; i += 64) {
      const float xs = use_lds ? s_act[i] : 0.5f * Xr[i];
      const float r = fmaxf(xs - tau_lo, 0.0f); s = fmaf(r, r, s);
    }
#pragma unroll
    for (int o = 32; o >= 1; o >>= 1) s += __shfl_xor(s, o);
    const float f_lo = s - 1.0f;

    float dm = tau_hi - tau_lo, tau_m = tau_lo;
    for (int it = 0; it < N_ITER; ++it) {
      dm *= 0.5f; tau_m = tau_lo + dm;
      float sm = 0.0f;
      for (int i = lane; i < n; i += 64) {
        const float xs = use_lds ? s_act[i] : 0.5f * Xr[i];
        const float r = fmaxf(xs - tau_m, 0.0f); sm = fmaf(r, r, sm);
      }
#pragma unroll
      for (int o = 32; o >= 1; o >>= 1) sm += __shfl_xor(sm, o);
      if ((sm - 1.0f) * f_lo >= 0.0f) tau_lo = tau_m;
    }
    float S = 0.0f, Q3 = 0.0f, PX = 0.0f;
    for (int i = lane; i < n; i += 64) {
      const float xs = use_lds ? s_act[i] : 0.5f * Xr[i];
      const float r = fmaxf(xs - tau_m, 0.0f);
      const float r2 = r * r;
      S += r2; Q3 += r2 * r; PX += r2 * (2.0f * xs);
    }
#pragma unroll
    for (int o = 32; o >= 1; o >>= 1) {
      S += __shfl_xor(S, o); Q3 += __shfl_xor(Q3, o); PX += __shfl_xor(PX, o);
    }
    if (lane == 0) {
      const float omega = (1.0f - Q3 / (S * sqrtf(S))) * (1.0f / 0.75f);
      atomicAdd(out, (omega + PX / S - sum_tx) * (1.0f / (float)B));
    }
  }
}

extern "C" void kernel_launch(void* const* d_in, const int* in_sizes, int n_in,
                              void* d_out, int out_size, void* d_ws, size_t ws_size,
                              hipStream_t stream) {
  const float* X = (const float*)d_in[0];
  const float* T = (const float*)d_in[1];
  float* out = (float*)d_out;
  const int rows = in_sizes[0] / V_DIM;
  const float invB = 1.0f / (float)rows;

  zero_out_kernel<<<1, 1, 0, stream>>>(out);

  const size_t need = (size_t)rows * 8 + (size_t)rows * CAP * 4;
  if (ws_size >= need) {
    int*   cnt_g  = (int*)d_ws;
    float* maxs_g = (float*)((char*)d_ws + (size_t)rows * 4);
    float* act_g  = (float*)((char*)d_ws + (size_t)rows * 8);
    rowstat_kernel<<<rows, TPB_A, 0, stream>>>(X, T, out, cnt_g, maxs_g, act_g, invB);
    bisect_kernel<<<(rows + 3) / 4, 256, 0, stream>>>(X, cnt_g, maxs_g, act_g, out, rows, invB);
  } else {
    entmax_loss_kernel<<<rows, TPB_A, 0, stream>>>(X, T, out, rows);
  }
}